// Round 1
// baseline (2012.829 us; speedup 1.0000x reference)
//
#include <hip/hip_runtime.h>
#include <math.h>

#define NB 2
#define COUT 128
#define EIN 4500
#define EOUT 9000
#define EPS 1e-5f

// ---------- generic tiled transpose: out[col][row] = in[row][col], per batch.
// out row (length R) lives at stride `ors` with column offset `oco`.
__global__ void transpose_kernel(const float* __restrict__ in, float* __restrict__ out,
                                 int R, int C, int ors, int oco) {
    __shared__ float tile[32][33];
    int b = blockIdx.z;
    int c0 = blockIdx.x * 32;   // tile over input cols (fast dim)
    int r0 = blockIdx.y * 32;   // tile over input rows
    const float* inb = in + (size_t)b * R * C;
    float* outb = out + (size_t)b * C * ors;
    int tx = threadIdx.x, ty = threadIdx.y;   // 32 x 8
    for (int i = 0; i < 32; i += 8) {
        int r = r0 + ty + i, c = c0 + tx;
        if (r < R && c < C) tile[ty + i][tx] = inb[(size_t)r * C + c];
    }
    __syncthreads();
    for (int i = 0; i < 32; i += 8) {
        int c = c0 + ty + i, r = r0 + tx;     // write out[c][r]
        if (r < R && c < C) outb[(size_t)c * ors + oco + r] = tile[tx][ty + i];
    }
}

// ---------- W [Cout][CIN][5] -> Wt [CIN*5][Cout]
__global__ void wtrans_kernel(const float* __restrict__ W, float* __restrict__ Wt, int K) {
    int i = blockIdx.x * 256 + threadIdx.x;   // over COUT*K
    if (i >= K * COUT) return;
    int o = i / K, r = i % K;
    Wt[(size_t)r * COUT + o] = W[i];
}

// ---------- extract 1-sparse column structure of unroll_mat
__global__ void parent_kernel(const float* __restrict__ mat, int* __restrict__ parent,
                              float* __restrict__ pval) {
    int eo = blockIdx.x * 256 + threadIdx.x;
    int b = blockIdx.y;
    if (eo >= EOUT) return;
    const float* m = mat + (size_t)b * EIN * EOUT + eo;
    int p = 0; float v = 0.f;
    for (int ei = 0; ei < EIN; ++ei) {
        float x = m[(size_t)ei * EOUT];
        if (x != 0.f) { p = ei; v = x; break; }
    }
    parent[b * EOUT + eo] = p;
    pval[b * EOUT + eo] = v;
}

// ---------- unpool: X_t[b][e][c] = Y1_t[b][parent[e]][c] * val[e]   (c < 128 part)
__global__ void unpool_kernel(const float* __restrict__ Y1t, const int* __restrict__ parent,
                              const float* __restrict__ pval, float* __restrict__ Xt) {
    int g = blockIdx.x * 256 + threadIdx.x;   // over NB*EOUT*COUT
    if (g >= NB * EOUT * COUT) return;
    int c = g & 127;
    int e = (g >> 7) % EOUT;
    int b = (g >> 7) / EOUT;
    int p = parent[b * EOUT + e];
    float v = pval[b * EOUT + e];
    Xt[((size_t)b * EOUT + e) * 256 + c] = Y1t[((size_t)b * EIN + p) * COUT + c] * v;
}

// ---------- mesh conv: Out[b][e][o] = sum_{c,k} g(c,k,e) * Wt[c*5+k][o] + bias[o]
// Xt edge-major [B][E][CIN]; 32 edges x 128 outs per block; 4x4 register tile/thread.
template <int CIN>
__global__ __launch_bounds__(256) void conv_kernel(
    const float* __restrict__ Xt, const int* __restrict__ gm,
    const float* __restrict__ Wt, const float* __restrict__ bias,
    float* __restrict__ Out, int E) {
    constexpr int KC = 80;            // 16 channels * 5 feats per chunk
    constexpr int NCH = CIN / 16;
    __shared__ float hs[KC * 36];     // [80][36] padded rows, 16B-aligned
    __shared__ float wsh[KC * 128];
    __shared__ int idx_lds[32][5];

    int b = blockIdx.y;
    int e0 = blockIdx.x * 32;
    int tid = threadIdx.x;

    if (tid < 160) {
        int e = tid / 5, k = tid % 5;
        int eg = e0 + e;
        idx_lds[e][k] = (eg < E) ? gm[((size_t)b * E + eg) * 5 + k] : 0;
    }

    int to = tid & 31, te = tid >> 5;
    int o4 = to * 4, e4 = te * 4;
    float acc[4][4];
#pragma unroll
    for (int i = 0; i < 4; ++i)
#pragma unroll
        for (int j = 0; j < 4; ++j) acc[i][j] = 0.f;

    const float* Xb = Xt + (size_t)b * E * CIN;
    int cl = tid & 15;   // channel within 16-chunk
    int eb = tid >> 4;   // 0..15

    for (int ch = 0; ch < NCH; ++ch) {
        __syncthreads();
        // stage W chunk [80][128]
        {
            const float* w0 = Wt + (size_t)ch * KC * 128;
#pragma unroll
            for (int i = 0; i < 10; ++i) {
                int l = (i * 256 + tid) * 4;
                *reinterpret_cast<float4*>(&wsh[l]) = *reinterpret_cast<const float4*>(&w0[l]);
            }
        }
        // stage symmetric features for 16 channels x 32 edges
        {
            int c = ch * 16 + cl;
#pragma unroll
            for (int eo_ = 0; eo_ < 2; ++eo_) {
                int e = eb + eo_ * 16;
                bool valid = (e0 + e) < E;
                float f[5];
#pragma unroll
                for (int k = 0; k < 5; ++k) {
                    int id = idx_lds[e][k];
                    f[k] = valid ? Xb[(size_t)id * CIN + c] : 0.f;
                }
                int kb = cl * 5;
                hs[(kb + 0) * 36 + e] = f[0];
                hs[(kb + 1) * 36 + e] = f[1] + f[3];
                hs[(kb + 2) * 36 + e] = f[2] + f[4];
                hs[(kb + 3) * 36 + e] = fabsf(f[1] - f[3]);
                hs[(kb + 4) * 36 + e] = fabsf(f[2] - f[4]);
            }
        }
        __syncthreads();
#pragma unroll 4
        for (int kk = 0; kk < KC; ++kk) {
            float4 hv = *reinterpret_cast<const float4*>(&hs[kk * 36 + e4]);
            float4 wv = *reinterpret_cast<const float4*>(&wsh[kk * 128 + o4]);
            float ha[4] = {hv.x, hv.y, hv.z, hv.w};
            float wa[4] = {wv.x, wv.y, wv.z, wv.w};
#pragma unroll
            for (int i = 0; i < 4; ++i)
#pragma unroll
                for (int j = 0; j < 4; ++j) acc[i][j] = fmaf(ha[i], wa[j], acc[i][j]);
        }
    }

    float4 bv = *reinterpret_cast<const float4*>(&bias[o4]);
    float bb[4] = {bv.x, bv.y, bv.z, bv.w};
#pragma unroll
    for (int i = 0; i < 4; ++i) {
        int e = e0 + e4 + i;
        if (e < E) {
            float4 r;
            r.x = acc[i][0] + bb[0];
            r.y = acc[i][1] + bb[1];
            r.z = acc[i][2] + bb[2];
            r.w = acc[i][3] + bb[3];
            *reinterpret_cast<float4*>(&Out[((size_t)b * E + e) * 128 + o4]) = r;
        }
    }
}

// ---------- per-(b,c) sum/sumsq partials (coalesced reads, atomic merge)
__global__ void stats_kernel(const float* __restrict__ Yt, float* __restrict__ stats, int E) {
    __shared__ float ssum[128], ssq[128];
    int b = blockIdx.y;
    int e0 = blockIdx.x * 64;
    int c = threadIdx.x & 127, eh = threadIdx.x >> 7;   // eh in {0,1}
    float s = 0.f, q = 0.f;
    for (int i = 0; i < 32; ++i) {
        int e = e0 + eh * 32 + i;
        if (e < E) {
            float v = Yt[((size_t)b * E + e) * 128 + c];
            s += v; q += v * v;
        }
    }
    if (eh == 0) { ssum[c] = s; ssq[c] = q; }
    __syncthreads();
    if (eh == 1) { ssum[c] += s; ssq[c] += q; }
    __syncthreads();
    if (threadIdx.x < 128) {
        atomicAdd(&stats[(b * 128 + threadIdx.x) * 2 + 0], ssum[threadIdx.x]);
        atomicAdd(&stats[(b * 128 + threadIdx.x) * 2 + 1], ssq[threadIdx.x]);
    }
}

// ---------- x1 = relu(instance_norm(y))
__global__ void norm_relu_kernel(const float* __restrict__ Yt, const float* __restrict__ stats,
                                 float* __restrict__ Out, int E) {
    int g = blockIdx.x * 256 + threadIdx.x;
    if (g >= NB * EOUT * 128) return;
    int c = g & 127;
    int e = (g >> 7) % E;
    int b = (g >> 7) / E;
    float invE = 1.0f / (float)E;
    float sum = stats[(b * 128 + c) * 2 + 0];
    float sq  = stats[(b * 128 + c) * 2 + 1];
    float mu = sum * invE;
    float var = sq * invE - mu * mu;
    float v = (Yt[g] - mu) * rsqrtf(var + EPS);
    Out[g] = v > 0.f ? v : 0.f;
}

// ---------- out[b][c][e] = relu(instance_norm(z) + x1), edge-major -> channel-major
__global__ void final_kernel(const float* __restrict__ Zt, const float* __restrict__ X1t,
                             const float* __restrict__ stats, float* __restrict__ out, int E) {
    __shared__ float tile[32 * 129];
    int b = blockIdx.y;
    int e0 = blockIdx.x * 32;
    int tid = threadIdx.x;
    float invE = 1.0f / (float)E;
#pragma unroll
    for (int i = 0; i < 16; ++i) {
        int idx = i * 256 + tid;      // 4096 = 32e x 128c
        int c = idx & 127, el = idx >> 7;
        int e = e0 + el;
        float v = 0.f;
        if (e < E) {
            float sum = stats[(b * 128 + c) * 2 + 0];
            float sq  = stats[(b * 128 + c) * 2 + 1];
            float mu = sum * invE;
            float var = sq * invE - mu * mu;
            float z = (Zt[((size_t)b * E + e) * 128 + c] - mu) * rsqrtf(var + EPS);
            v = z + X1t[((size_t)b * E + e) * 128 + c];
            v = v > 0.f ? v : 0.f;
        }
        tile[el * 129 + c] = v;
    }
    __syncthreads();
#pragma unroll
    for (int i = 0; i < 16; ++i) {
        int idx = i * 256 + tid;
        int el = idx & 31, c = idx >> 5;
        int e = e0 + el;
        if (e < E) out[((size_t)b * 128 + c) * E + e] = tile[el * 129 + c];
    }
}

extern "C" void kernel_launch(void* const* d_in, const int* in_sizes, int n_in,
                              void* d_out, int out_size, void* d_ws, size_t ws_size,
                              hipStream_t stream) {
    const float* from_up   = (const float*)d_in[0];
    const float* from_down = (const float*)d_in[1];
    const float* unroll    = (const float*)d_in[2];
    const float* W_up      = (const float*)d_in[3];
    const float* b_up      = (const float*)d_in[4];
    const float* W1        = (const float*)d_in[5];
    const float* b1        = (const float*)d_in[6];
    const float* W2        = (const float*)d_in[7];
    const float* b2        = (const float*)d_in[8];
    const int* gemm_up     = (const int*)d_in[9];
    const int* gemm_post   = (const int*)d_in[10];
    float* out = (float*)d_out;

    float* ws = (float*)d_ws;
    size_t off = 0;
    auto alloc = [&](size_t n) { float* p = ws + off; off += n; return p; };
    float* Xup_t = alloc((size_t)NB * EIN * 256);    // from_up edge-major
    float* Wup_t = alloc(1280 * 128);
    float* W1_t  = alloc(1280 * 128);
    float* W2_t  = alloc(640 * 128);
    float* Y1_t  = alloc((size_t)NB * EIN * 128);    // up-conv out
    float* X_t   = alloc((size_t)NB * EOUT * 256);   // concat input, edge-major
    float* Y2_t  = alloc((size_t)NB * EOUT * 128);   // conv1 out
    float* X1_t  = alloc((size_t)NB * EOUT * 128);   // post norm+relu
    float* Y3_t  = alloc((size_t)NB * EOUT * 128);   // conv2 out
    float* stats = alloc(1024);                       // stats1 (512) + stats2 (512)
    int*   parent = (int*)alloc(NB * EOUT);
    float* pval  = alloc(NB * EOUT);
    float* stats1 = stats, *stats2 = stats + 512;

    hipMemsetAsync(stats, 0, 1024 * sizeof(float), stream);

    dim3 tb(32, 8);
    // from_up [b][256][4500] -> Xup_t [b][4500][256]
    transpose_kernel<<<dim3(141, 8, NB), tb, 0, stream>>>(from_up, Xup_t, 256, EIN, 256, 0);
    // from_down [b][128][9000] -> X_t[b][e][128..255]
    transpose_kernel<<<dim3(282, 4, NB), tb, 0, stream>>>(from_down, X_t, 128, EOUT, 256, 128);
    wtrans_kernel<<<640, 256, 0, stream>>>(W_up, Wup_t, 1280);
    wtrans_kernel<<<640, 256, 0, stream>>>(W1, W1_t, 1280);
    wtrans_kernel<<<320, 256, 0, stream>>>(W2, W2_t, 640);
    parent_kernel<<<dim3(36, NB), 256, 0, stream>>>(unroll, parent, pval);

    // up conv on Ein
    conv_kernel<256><<<dim3(141, NB), 256, 0, stream>>>(Xup_t, gemm_up, Wup_t, b_up, Y1_t, EIN);
    // unpool into X_t channels 0..127
    unpool_kernel<<<9000, 256, 0, stream>>>(Y1_t, parent, pval, X_t);
    // conv1
    conv_kernel<256><<<dim3(282, NB), 256, 0, stream>>>(X_t, gemm_post, W1_t, b1, Y2_t, EOUT);
    stats_kernel<<<dim3(141, NB), 256, 0, stream>>>(Y2_t, stats1, EOUT);
    norm_relu_kernel<<<9000, 256, 0, stream>>>(Y2_t, stats1, X1_t, EOUT);
    // conv2
    conv_kernel<128><<<dim3(282, NB), 256, 0, stream>>>(X1_t, gemm_post, W2_t, b2, Y3_t, EOUT);
    stats_kernel<<<dim3(141, NB), 256, 0, stream>>>(Y3_t, stats2, EOUT);
    final_kernel<<<dim3(282, NB), 256, 0, stream>>>(Y3_t, X1_t, stats2, out, EOUT);
}

// Round 2
// 414.312 us; speedup vs baseline: 4.8582x; 4.8582x over previous
//
#include <hip/hip_runtime.h>
#include <math.h>

#define NB 2
#define COUT 128
#define EIN 4500
#define EOUT 9000
#define EPS 1e-5f

// ---------- generic tiled transpose: out[col][row] = in[row][col], per batch.
// out row (length R) lives at stride `ors` with column offset `oco`.
__global__ void transpose_kernel(const float* __restrict__ in, float* __restrict__ out,
                                 int R, int C, int ors, int oco) {
    __shared__ float tile[32][33];
    int b = blockIdx.z;
    int c0 = blockIdx.x * 32;   // tile over input cols (fast dim)
    int r0 = blockIdx.y * 32;   // tile over input rows
    const float* inb = in + (size_t)b * R * C;
    float* outb = out + (size_t)b * C * ors;
    int tx = threadIdx.x, ty = threadIdx.y;   // 32 x 8
    for (int i = 0; i < 32; i += 8) {
        int r = r0 + ty + i, c = c0 + tx;
        if (r < R && c < C) tile[ty + i][tx] = inb[(size_t)r * C + c];
    }
    __syncthreads();
    for (int i = 0; i < 32; i += 8) {
        int c = c0 + ty + i, r = r0 + tx;     // write out[c][r]
        if (r < R && c < C) outb[(size_t)c * ors + oco + r] = tile[tx][ty + i];
    }
}

// ---------- W [Cout][CIN][5] -> Wt [CIN*5][Cout]
__global__ void wtrans_kernel(const float* __restrict__ W, float* __restrict__ Wt, int K) {
    int i = blockIdx.x * 256 + threadIdx.x;   // over COUT*K
    if (i >= K * COUT) return;
    int o = i / K, r = i % K;
    Wt[(size_t)r * COUT + o] = W[i];
}

// ---------- extract 1-sparse column structure of unroll_mat, COALESCED:
// grid-stride float4 sweep over all B*EIN*EOUT entries; nonzeros are scattered
// (<= 1 per column in the given data) so plain stores suffice. pval pre-zeroed.
__global__ void parent_scan_kernel(const float* __restrict__ mat, int* __restrict__ parent,
                                   float* __restrict__ pval) {
    const size_t total4 = (size_t)NB * EIN * EOUT / 4;   // 20,250,000
    size_t stride = (size_t)gridDim.x * blockDim.x;
    for (size_t i = (size_t)blockIdx.x * blockDim.x + threadIdx.x; i < total4; i += stride) {
        float4 v = reinterpret_cast<const float4*>(mat)[i];
        if (v.x != 0.f || v.y != 0.f || v.z != 0.f || v.w != 0.f) {
            float a[4] = {v.x, v.y, v.z, v.w};
#pragma unroll
            for (int j = 0; j < 4; ++j) {
                if (a[j] != 0.f) {
                    size_t idx = i * 4 + j;
                    int eo = (int)(idx % EOUT);
                    size_t t = idx / EOUT;
                    int ei = (int)(t % EIN);
                    int b = (int)(t / EIN);
                    parent[b * EOUT + eo] = ei;
                    pval[b * EOUT + eo] = a[j];
                }
            }
        }
    }
}

// ---------- unpool: X_t[b][e][c] = Y1_t[b][parent[e]][c] * val[e]   (c < 128 part)
__global__ void unpool_kernel(const float* __restrict__ Y1t, const int* __restrict__ parent,
                              const float* __restrict__ pval, float* __restrict__ Xt) {
    int g = blockIdx.x * 256 + threadIdx.x;   // over NB*EOUT*COUT
    if (g >= NB * EOUT * COUT) return;
    int c = g & 127;
    int e = (g >> 7) % EOUT;
    int b = (g >> 7) / EOUT;
    int p = parent[b * EOUT + e];
    float v = pval[b * EOUT + e];
    Xt[((size_t)b * EOUT + e) * 256 + c] = Y1t[((size_t)b * EIN + p) * COUT + c] * v;
}

// ---------- mesh conv: Out[b][e][o] = sum_{c,k} g(c,k,e) * Wt[c*5+k][o] + bias[o]
// Xt edge-major [B][E][CIN]; 32 edges x 128 outs per block; 4x4 register tile/thread.
template <int CIN>
__global__ __launch_bounds__(256) void conv_kernel(
    const float* __restrict__ Xt, const int* __restrict__ gm,
    const float* __restrict__ Wt, const float* __restrict__ bias,
    float* __restrict__ Out, int E) {
    constexpr int KC = 80;            // 16 channels * 5 feats per chunk
    constexpr int NCH = CIN / 16;
    __shared__ float hs[KC * 36];     // [80][36] padded rows, 16B-aligned
    __shared__ float wsh[KC * 128];
    __shared__ int idx_lds[32][5];

    int b = blockIdx.y;
    int e0 = blockIdx.x * 32;
    int tid = threadIdx.x;

    if (tid < 160) {
        int e = tid / 5, k = tid % 5;
        int eg = e0 + e;
        idx_lds[e][k] = (eg < E) ? gm[((size_t)b * E + eg) * 5 + k] : 0;
    }

    int to = tid & 31, te = tid >> 5;
    int o4 = to * 4, e4 = te * 4;
    float acc[4][4];
#pragma unroll
    for (int i = 0; i < 4; ++i)
#pragma unroll
        for (int j = 0; j < 4; ++j) acc[i][j] = 0.f;

    const float* Xb = Xt + (size_t)b * E * CIN;
    int cl = tid & 15;   // channel within 16-chunk
    int eb = tid >> 4;   // 0..15

    for (int ch = 0; ch < NCH; ++ch) {
        __syncthreads();
        // stage W chunk [80][128]
        {
            const float* w0 = Wt + (size_t)ch * KC * 128;
#pragma unroll
            for (int i = 0; i < 10; ++i) {
                int l = (i * 256 + tid) * 4;
                *reinterpret_cast<float4*>(&wsh[l]) = *reinterpret_cast<const float4*>(&w0[l]);
            }
        }
        // stage symmetric features for 16 channels x 32 edges
        {
            int c = ch * 16 + cl;
#pragma unroll
            for (int eo_ = 0; eo_ < 2; ++eo_) {
                int e = eb + eo_ * 16;
                bool valid = (e0 + e) < E;
                float f[5];
#pragma unroll
                for (int k = 0; k < 5; ++k) {
                    int id = idx_lds[e][k];
                    f[k] = valid ? Xb[(size_t)id * CIN + c] : 0.f;
                }
                int kb = cl * 5;
                hs[(kb + 0) * 36 + e] = f[0];
                hs[(kb + 1) * 36 + e] = f[1] + f[3];
                hs[(kb + 2) * 36 + e] = f[2] + f[4];
                hs[(kb + 3) * 36 + e] = fabsf(f[1] - f[3]);
                hs[(kb + 4) * 36 + e] = fabsf(f[2] - f[4]);
            }
        }
        __syncthreads();
#pragma unroll 4
        for (int kk = 0; kk < KC; ++kk) {
            float4 hv = *reinterpret_cast<const float4*>(&hs[kk * 36 + e4]);
            float4 wv = *reinterpret_cast<const float4*>(&wsh[kk * 128 + o4]);
            float ha[4] = {hv.x, hv.y, hv.z, hv.w};
            float wa[4] = {wv.x, wv.y, wv.z, wv.w};
#pragma unroll
            for (int i = 0; i < 4; ++i)
#pragma unroll
                for (int j = 0; j < 4; ++j) acc[i][j] = fmaf(ha[i], wa[j], acc[i][j]);
        }
    }

    float4 bv = *reinterpret_cast<const float4*>(&bias[o4]);
    float bb[4] = {bv.x, bv.y, bv.z, bv.w};
#pragma unroll
    for (int i = 0; i < 4; ++i) {
        int e = e0 + e4 + i;
        if (e < E) {
            float4 r;
            r.x = acc[i][0] + bb[0];
            r.y = acc[i][1] + bb[1];
            r.z = acc[i][2] + bb[2];
            r.w = acc[i][3] + bb[3];
            *reinterpret_cast<float4*>(&Out[((size_t)b * E + e) * 128 + o4]) = r;
        }
    }
}

// ---------- per-(b,c) sum/sumsq partials (coalesced reads, atomic merge)
__global__ void stats_kernel(const float* __restrict__ Yt, float* __restrict__ stats, int E) {
    __shared__ float ssum[128], ssq[128];
    int b = blockIdx.y;
    int e0 = blockIdx.x * 64;
    int c = threadIdx.x & 127, eh = threadIdx.x >> 7;   // eh in {0,1}
    float s = 0.f, q = 0.f;
    for (int i = 0; i < 32; ++i) {
        int e = e0 + eh * 32 + i;
        if (e < E) {
            float v = Yt[((size_t)b * E + e) * 128 + c];
            s += v; q += v * v;
        }
    }
    if (eh == 0) { ssum[c] = s; ssq[c] = q; }
    __syncthreads();
    if (eh == 1) { ssum[c] += s; ssq[c] += q; }
    __syncthreads();
    if (threadIdx.x < 128) {
        atomicAdd(&stats[(b * 128 + threadIdx.x) * 2 + 0], ssum[threadIdx.x]);
        atomicAdd(&stats[(b * 128 + threadIdx.x) * 2 + 1], ssq[threadIdx.x]);
    }
}

// ---------- x1 = relu(instance_norm(y))
__global__ void norm_relu_kernel(const float* __restrict__ Yt, const float* __restrict__ stats,
                                 float* __restrict__ Out, int E) {
    int g = blockIdx.x * 256 + threadIdx.x;
    if (g >= NB * EOUT * 128) return;
    int c = g & 127;
    int e = (g >> 7) % E;
    int b = (g >> 7) / E;
    float invE = 1.0f / (float)E;
    float sum = stats[(b * 128 + c) * 2 + 0];
    float sq  = stats[(b * 128 + c) * 2 + 1];
    float mu = sum * invE;
    float var = sq * invE - mu * mu;
    float v = (Yt[g] - mu) * rsqrtf(var + EPS);
    Out[g] = v > 0.f ? v : 0.f;
}

// ---------- out[b][c][e] = relu(instance_norm(z) + x1), edge-major -> channel-major
__global__ void final_kernel(const float* __restrict__ Zt, const float* __restrict__ X1t,
                             const float* __restrict__ stats, float* __restrict__ out, int E) {
    __shared__ float tile[32 * 129];
    int b = blockIdx.y;
    int e0 = blockIdx.x * 32;
    int tid = threadIdx.x;
    float invE = 1.0f / (float)E;
#pragma unroll
    for (int i = 0; i < 16; ++i) {
        int idx = i * 256 + tid;      // 4096 = 32e x 128c
        int c = idx & 127, el = idx >> 7;
        int e = e0 + el;
        float v = 0.f;
        if (e < E) {
            float sum = stats[(b * 128 + c) * 2 + 0];
            float sq  = stats[(b * 128 + c) * 2 + 1];
            float mu = sum * invE;
            float var = sq * invE - mu * mu;
            float z = (Zt[((size_t)b * E + e) * 128 + c] - mu) * rsqrtf(var + EPS);
            v = z + X1t[((size_t)b * E + e) * 128 + c];
            v = v > 0.f ? v : 0.f;
        }
        tile[el * 129 + c] = v;
    }
    __syncthreads();
#pragma unroll
    for (int i = 0; i < 16; ++i) {
        int idx = i * 256 + tid;
        int el = idx & 31, c = idx >> 5;
        int e = e0 + el;
        if (e < E) out[((size_t)b * 128 + c) * E + e] = tile[el * 129 + c];
    }
}

extern "C" void kernel_launch(void* const* d_in, const int* in_sizes, int n_in,
                              void* d_out, int out_size, void* d_ws, size_t ws_size,
                              hipStream_t stream) {
    const float* from_up   = (const float*)d_in[0];
    const float* from_down = (const float*)d_in[1];
    const float* unroll    = (const float*)d_in[2];
    const float* W_up      = (const float*)d_in[3];
    const float* b_up      = (const float*)d_in[4];
    const float* W1        = (const float*)d_in[5];
    const float* b1        = (const float*)d_in[6];
    const float* W2        = (const float*)d_in[7];
    const float* b2        = (const float*)d_in[8];
    const int* gemm_up     = (const int*)d_in[9];
    const int* gemm_post   = (const int*)d_in[10];
    float* out = (float*)d_out;

    float* ws = (float*)d_ws;
    size_t off = 0;
    auto alloc = [&](size_t n) { float* p = ws + off; off += n; return p; };
    float* Xup_t = alloc((size_t)NB * EIN * 256);    // from_up edge-major
    float* Wup_t = alloc(1280 * 128);
    float* W1_t  = alloc(1280 * 128);
    float* W2_t  = alloc(640 * 128);
    float* Y1_t  = alloc((size_t)NB * EIN * 128);    // up-conv out
    float* X_t   = alloc((size_t)NB * EOUT * 256);   // concat input, edge-major
    float* Y2_t  = alloc((size_t)NB * EOUT * 128);   // conv1 out
    float* X1_t  = alloc((size_t)NB * EOUT * 128);   // post norm+relu
    float* Y3_t  = alloc((size_t)NB * EOUT * 128);   // conv2 out
    float* stats = alloc(1024);                       // stats1 (512) + stats2 (512)
    int*   parent = (int*)alloc(NB * EOUT);
    float* pval  = alloc(NB * EOUT);
    float* stats1 = stats, *stats2 = stats + 512;

    hipMemsetAsync(stats, 0, 1024 * sizeof(float), stream);
    hipMemsetAsync(parent, 0, NB * EOUT * sizeof(int), stream);
    hipMemsetAsync(pval, 0, NB * EOUT * sizeof(float), stream);

    dim3 tb(32, 8);
    // from_up [b][256][4500] -> Xup_t [b][4500][256]
    transpose_kernel<<<dim3(141, 8, NB), tb, 0, stream>>>(from_up, Xup_t, 256, EIN, 256, 0);
    // from_down [b][128][9000] -> X_t[b][e][128..255]
    transpose_kernel<<<dim3(282, 4, NB), tb, 0, stream>>>(from_down, X_t, 128, EOUT, 256, 128);
    wtrans_kernel<<<640, 256, 0, stream>>>(W_up, Wup_t, 1280);
    wtrans_kernel<<<640, 256, 0, stream>>>(W1, W1_t, 1280);
    wtrans_kernel<<<320, 256, 0, stream>>>(W2, W2_t, 640);
    parent_scan_kernel<<<2048, 256, 0, stream>>>(unroll, parent, pval);

    // up conv on Ein
    conv_kernel<256><<<dim3(141, NB), 256, 0, stream>>>(Xup_t, gemm_up, Wup_t, b_up, Y1_t, EIN);
    // unpool into X_t channels 0..127
    unpool_kernel<<<9000, 256, 0, stream>>>(Y1_t, parent, pval, X_t);
    // conv1
    conv_kernel<256><<<dim3(282, NB), 256, 0, stream>>>(X_t, gemm_post, W1_t, b1, Y2_t, EOUT);
    stats_kernel<<<dim3(141, NB), 256, 0, stream>>>(Y2_t, stats1, EOUT);
    norm_relu_kernel<<<9000, 256, 0, stream>>>(Y2_t, stats1, X1_t, EOUT);
    // conv2
    conv_kernel<128><<<dim3(282, NB), 256, 0, stream>>>(X1_t, gemm_post, W2_t, b2, Y3_t, EOUT);
    stats_kernel<<<dim3(141, NB), 256, 0, stream>>>(Y3_t, stats2, EOUT);
    final_kernel<<<dim3(282, NB), 256, 0, stream>>>(Y3_t, X1_t, stats2, out, EOUT);
}

// Round 3
// 302.511 us; speedup vs baseline: 6.6537x; 1.3696x over previous
//
#include <hip/hip_runtime.h>
#include <math.h>

#define NB 2
#define COUT 128
#define EIN 4500
#define EOUT 9000
#define EPS 1e-5f

typedef __attribute__((ext_vector_type(8))) short bf16x8;
typedef __attribute__((ext_vector_type(4))) float f32x4;

__device__ inline uint32_t bfr(float x) {
    uint32_t u = __float_as_uint(x);
    return (u + 0x7fffu + ((u >> 16) & 1u)) >> 16;
}
__device__ inline uint32_t pk2(float a, float b) { return bfr(a) | (bfr(b) << 16); }

// ---------- zero stats/parent/pval (replaces hipMemsetAsync fills)
__global__ void init_kernel(float* __restrict__ stats, int* __restrict__ parent,
                            float* __restrict__ pval) {
    int i = blockIdx.x * 256 + threadIdx.x;
    if (i < 1024) stats[i] = 0.f;
    if (i < NB * EOUT) { parent[i] = 0; pval[i] = 0.f; }
}

// ---------- generic tiled transpose: out[col][row] = in[row][col], per batch.
__global__ void transpose_kernel(const float* __restrict__ in, float* __restrict__ out,
                                 int R, int C, int ors, int oco) {
    __shared__ float tile[32][33];
    int b = blockIdx.z;
    int c0 = blockIdx.x * 32;
    int r0 = blockIdx.y * 32;
    const float* inb = in + (size_t)b * R * C;
    float* outb = out + (size_t)b * C * ors;
    int tx = threadIdx.x, ty = threadIdx.y;   // 32 x 8
    for (int i = 0; i < 32; i += 8) {
        int r = r0 + ty + i, c = c0 + tx;
        if (r < R && c < C) tile[ty + i][tx] = inb[(size_t)r * C + c];
    }
    __syncthreads();
    for (int i = 0; i < 32; i += 8) {
        int c = c0 + ty + i, r = r0 + tx;
        if (r < R && c < C) outb[(size_t)c * ors + oco + r] = tile[tx][ty + i];
    }
}

// ---------- W [128][CIN][5] f32 -> Wp [128][CIN*8] bf16 (k' = c*8+f, 3 zero pads)
__global__ void wpack_kernel(const float* __restrict__ W, ushort* __restrict__ Wp, int n) {
    int i = blockIdx.x * 256 + threadIdx.x;   // over 128*CIN
    if (i >= n) return;
    const float* src = W + (size_t)i * 5;
    uint4 v;
    v.x = pk2(src[0], src[1]);
    v.y = pk2(src[2], src[3]);
    v.z = pk2(src[4], 0.f);
    v.w = 0u;
    *reinterpret_cast<uint4*>(Wp + (size_t)i * 8) = v;
}

// ---------- coalesced 1-sparse column extraction of unroll_mat
__global__ void parent_scan_kernel(const float* __restrict__ mat, int* __restrict__ parent,
                                   float* __restrict__ pval) {
    const size_t total4 = (size_t)NB * EIN * EOUT / 4;
    size_t stride = (size_t)gridDim.x * blockDim.x;
    for (size_t i = (size_t)blockIdx.x * blockDim.x + threadIdx.x; i < total4; i += stride) {
        float4 v = reinterpret_cast<const float4*>(mat)[i];
        if (v.x != 0.f || v.y != 0.f || v.z != 0.f || v.w != 0.f) {
            float a[4] = {v.x, v.y, v.z, v.w};
#pragma unroll
            for (int j = 0; j < 4; ++j) {
                if (a[j] != 0.f) {
                    size_t idx = i * 4 + j;
                    int eo = (int)(idx % EOUT);
                    size_t t = idx / EOUT;
                    int ei = (int)(t % EIN);
                    int b = (int)(t / EIN);
                    parent[b * EOUT + eo] = ei;
                    pval[b * EOUT + eo] = a[j];
                }
            }
        }
    }
}

// ---------- unpool: X_t[b][e][c] = Y1_t[b][parent[e]][c] * val[e]   (c < 128 part)
__global__ void unpool_kernel(const float* __restrict__ Y1t, const int* __restrict__ parent,
                              const float* __restrict__ pval, float* __restrict__ Xt) {
    int g = blockIdx.x * 256 + threadIdx.x;
    if (g >= NB * EOUT * COUT) return;
    int c = g & 127;
    int e = (g >> 7) % EOUT;
    int b = (g >> 7) / EOUT;
    int p = parent[b * EOUT + e];
    float v = pval[b * EOUT + e];
    Xt[((size_t)b * EOUT + e) * 256 + c] = Y1t[((size_t)b * EIN + p) * COUT + c] * v;
}

// ---------- MFMA mesh conv.
// Xt edge-major [B][E][CIN] f32; Wp [128][CIN*8] bf16; Out [B][E][128] f32.
// Block: 64 edges x 128 outs, 4 waves (o-split 32 each).
// K' = CIN*8, chunks of 128 k' (16 channels), 4 MFMA K-steps per chunk.
template <int CIN>
__global__ __launch_bounds__(256) void conv_mfma(
    const float* __restrict__ Xt, const int* __restrict__ gm,
    const ushort* __restrict__ Wp, const float* __restrict__ bias,
    float* __restrict__ Out, int E) {
    constexpr int NCH = CIN / 16;
    constexpr int KP = CIN * 8;
    constexpr int LDW = 136;          // row stride (bf16) : 272 B -> bank+4/row, 2-way free
    __shared__ __align__(16) ushort Gs[64 * LDW];
    __shared__ __align__(16) ushort Ws[128 * LDW];
    __shared__ int idx[64 * 5];

    int tid = threadIdx.x;
    int b = blockIdx.y, e0 = blockIdx.x * 64;

    for (int i = tid; i < 320; i += 256) {
        int e = i / 5, k = i % 5;
        int eg = e0 + e;
        idx[i] = (eg < E) ? gm[((size_t)b * E + eg) * 5 + k] : 0;
    }

    const float* Xb = Xt + (size_t)b * E * CIN;
    int l = tid & 63, w = tid >> 6;
    int lr = l & 15, lg = l >> 4;

    f32x4 acc[4][2];
#pragma unroll
    for (int et = 0; et < 4; ++et)
#pragma unroll
        for (int ot = 0; ot < 2; ++ot) acc[et][ot] = (f32x4)0.f;

    int clc = tid & 15;    // channel-local 0..15 (lane-consecutive -> coalesced gathers)
    int ebs = tid >> 4;    // 0..15

    for (int ch = 0; ch < NCH; ++ch) {
        __syncthreads();
        // stage W chunk: [128 o][128 k'] bf16
        {
            int o = tid >> 1, h = tid & 1;
            const ushort* src = Wp + (size_t)o * KP + ch * 128 + h * 64;
            ushort* dst = Ws + o * LDW + h * 64;
#pragma unroll
            for (int i = 0; i < 8; ++i)
                *reinterpret_cast<uint4*>(dst + i * 8) =
                    *reinterpret_cast<const uint4*>(src + i * 8);
        }
        // stage G chunk: [64 e][16 c * 8 k'] bf16, one b128 write per (e,c)
        {
            int c = ch * 16 + clc;
#pragma unroll
            for (int i = 0; i < 4; ++i) {
                int e = i * 16 + ebs;
                bool valid = (e0 + e) < E;
                float f0 = 0.f, f1 = 0.f, f2 = 0.f, f3 = 0.f, f4 = 0.f;
                if (valid) {
                    const int* ip = &idx[e * 5];
                    f0 = Xb[(size_t)ip[0] * CIN + c];
                    f1 = Xb[(size_t)ip[1] * CIN + c];
                    f2 = Xb[(size_t)ip[2] * CIN + c];
                    f3 = Xb[(size_t)ip[3] * CIN + c];
                    f4 = Xb[(size_t)ip[4] * CIN + c];
                }
                uint4 v;
                v.x = pk2(f0, f1 + f3);
                v.y = pk2(f2 + f4, fabsf(f1 - f3));
                v.z = pk2(fabsf(f2 - f4), 0.f);
                v.w = 0u;
                *reinterpret_cast<uint4*>(Gs + e * LDW + clc * 8) = v;
            }
        }
        __syncthreads();
#pragma unroll
        for (int ks = 0; ks < 4; ++ks) {
            bf16x8 a[4], bb[2];
#pragma unroll
            for (int et = 0; et < 4; ++et)
                a[et] = *reinterpret_cast<const bf16x8*>(Gs + (et * 16 + lr) * LDW + ks * 32 + lg * 8);
#pragma unroll
            for (int ot = 0; ot < 2; ++ot)
                bb[ot] = *reinterpret_cast<const bf16x8*>(Ws + (w * 32 + ot * 16 + lr) * LDW + ks * 32 + lg * 8);
#pragma unroll
            for (int et = 0; et < 4; ++et)
#pragma unroll
                for (int ot = 0; ot < 2; ++ot)
                    acc[et][ot] = __builtin_amdgcn_mfma_f32_16x16x32_bf16(a[et], bb[ot], acc[et][ot], 0, 0, 0);
        }
    }

    // epilogue: D frag: col = lane&15 (=o), row = (lane>>4)*4 + r (=edge)
#pragma unroll
    for (int ot = 0; ot < 2; ++ot) {
        int o = w * 32 + ot * 16 + lr;
        float bv = bias[o];
#pragma unroll
        for (int et = 0; et < 4; ++et) {
#pragma unroll
            for (int r = 0; r < 4; ++r) {
                int e = e0 + et * 16 + lg * 4 + r;
                if (e < E) Out[((size_t)b * E + e) * 128 + o] = acc[et][ot][r] + bv;
            }
        }
    }
}

// ---------- per-(b,c) sum/sumsq partials (coalesced reads, atomic merge)
__global__ void stats_kernel(const float* __restrict__ Yt, float* __restrict__ stats, int E) {
    __shared__ float ssum[128], ssq[128];
    int b = blockIdx.y;
    int e0 = blockIdx.x * 64;
    int c = threadIdx.x & 127, eh = threadIdx.x >> 7;
    float s = 0.f, q = 0.f;
    for (int i = 0; i < 32; ++i) {
        int e = e0 + eh * 32 + i;
        if (e < E) {
            float v = Yt[((size_t)b * E + e) * 128 + c];
            s += v; q += v * v;
        }
    }
    if (eh == 0) { ssum[c] = s; ssq[c] = q; }
    __syncthreads();
    if (eh == 1) { ssum[c] += s; ssq[c] += q; }
    __syncthreads();
    if (threadIdx.x < 128) {
        atomicAdd(&stats[(b * 128 + threadIdx.x) * 2 + 0], ssum[threadIdx.x]);
        atomicAdd(&stats[(b * 128 + threadIdx.x) * 2 + 1], ssq[threadIdx.x]);
    }
}

// ---------- x1 = relu(instance_norm(y))
__global__ void norm_relu_kernel(const float* __restrict__ Yt, const float* __restrict__ stats,
                                 float* __restrict__ Out, int E) {
    int g = blockIdx.x * 256 + threadIdx.x;
    if (g >= NB * EOUT * 128) return;
    int c = g & 127;
    int b = (g >> 7) / E;
    float invE = 1.0f / (float)E;
    float sum = stats[(b * 128 + c) * 2 + 0];
    float sq  = stats[(b * 128 + c) * 2 + 1];
    float mu = sum * invE;
    float var = sq * invE - mu * mu;
    float v = (Yt[g] - mu) * rsqrtf(var + EPS);
    Out[g] = v > 0.f ? v : 0.f;
}

// ---------- out[b][c][e] = relu(instance_norm(z) + x1), edge-major -> channel-major
__global__ void final_kernel(const float* __restrict__ Zt, const float* __restrict__ X1t,
                             const float* __restrict__ stats, float* __restrict__ out, int E) {
    __shared__ float tile[32 * 129];
    int b = blockIdx.y;
    int e0 = blockIdx.x * 32;
    int tid = threadIdx.x;
    float invE = 1.0f / (float)E;
#pragma unroll
    for (int i = 0; i < 16; ++i) {
        int idx = i * 256 + tid;
        int c = idx & 127, el = idx >> 7;
        int e = e0 + el;
        float v = 0.f;
        if (e < E) {
            float sum = stats[(b * 128 + c) * 2 + 0];
            float sq  = stats[(b * 128 + c) * 2 + 1];
            float mu = sum * invE;
            float var = sq * invE - mu * mu;
            float z = (Zt[((size_t)b * E + e) * 128 + c] - mu) * rsqrtf(var + EPS);
            v = z + X1t[((size_t)b * E + e) * 128 + c];
            v = v > 0.f ? v : 0.f;
        }
        tile[el * 129 + c] = v;
    }
    __syncthreads();
#pragma unroll
    for (int i = 0; i < 16; ++i) {
        int idx = i * 256 + tid;
        int el = idx & 31, c = idx >> 5;
        int e = e0 + el;
        if (e < E) out[((size_t)b * 128 + c) * E + e] = tile[el * 129 + c];
    }
}

extern "C" void kernel_launch(void* const* d_in, const int* in_sizes, int n_in,
                              void* d_out, int out_size, void* d_ws, size_t ws_size,
                              hipStream_t stream) {
    const float* from_up   = (const float*)d_in[0];
    const float* from_down = (const float*)d_in[1];
    const float* unroll    = (const float*)d_in[2];
    const float* W_up      = (const float*)d_in[3];
    const float* b_up      = (const float*)d_in[4];
    const float* W1        = (const float*)d_in[5];
    const float* b1        = (const float*)d_in[6];
    const float* W2        = (const float*)d_in[7];
    const float* b2        = (const float*)d_in[8];
    const int* gemm_up     = (const int*)d_in[9];
    const int* gemm_post   = (const int*)d_in[10];
    float* out = (float*)d_out;

    float* ws = (float*)d_ws;
    size_t off = 0;
    auto alloc = [&](size_t n) { float* p = ws + off; off += n; return p; };
    float* Xup_t = alloc((size_t)NB * EIN * 256);       // from_up edge-major
    ushort* Wp_up = (ushort*)alloc(131072);             // [128][2048] bf16
    ushort* Wp_1  = (ushort*)alloc(131072);             // [128][2048] bf16
    ushort* Wp_2  = (ushort*)alloc(65536);              // [128][1024] bf16
    float* Y1_t  = alloc((size_t)NB * EIN * 128);       // up-conv out
    float* X_t   = alloc((size_t)NB * EOUT * 256);      // concat input, edge-major
    float* Y2_t  = alloc((size_t)NB * EOUT * 128);      // conv1 out
    float* X1_t  = alloc((size_t)NB * EOUT * 128);      // post norm+relu
    float* Y3_t  = alloc((size_t)NB * EOUT * 128);      // conv2 out
    float* stats = alloc(1024);
    int*   parent = (int*)alloc(NB * EOUT);
    float* pval  = alloc(NB * EOUT);
    float* stats1 = stats, *stats2 = stats + 512;

    init_kernel<<<71, 256, 0, stream>>>(stats, parent, pval);

    dim3 tb(32, 8);
    transpose_kernel<<<dim3(141, 8, NB), tb, 0, stream>>>(from_up, Xup_t, 256, EIN, 256, 0);
    transpose_kernel<<<dim3(282, 4, NB), tb, 0, stream>>>(from_down, X_t, 128, EOUT, 256, 128);
    wpack_kernel<<<128, 256, 0, stream>>>(W_up, Wp_up, 128 * 256);
    wpack_kernel<<<128, 256, 0, stream>>>(W1, Wp_1, 128 * 256);
    wpack_kernel<<<64, 256, 0, stream>>>(W2, Wp_2, 128 * 128);
    parent_scan_kernel<<<2048, 256, 0, stream>>>(unroll, parent, pval);

    conv_mfma<256><<<dim3(71, NB), 256, 0, stream>>>(Xup_t, gemm_up, Wp_up, b_up, Y1_t, EIN);
    unpool_kernel<<<9000, 256, 0, stream>>>(Y1_t, parent, pval, X_t);
    conv_mfma<256><<<dim3(141, NB), 256, 0, stream>>>(X_t, gemm_post, Wp_1, b1, Y2_t, EOUT);
    stats_kernel<<<dim3(141, NB), 256, 0, stream>>>(Y2_t, stats1, EOUT);
    norm_relu_kernel<<<9000, 256, 0, stream>>>(Y2_t, stats1, X1_t, EOUT);
    conv_mfma<128><<<dim3(141, NB), 256, 0, stream>>>(X1_t, gemm_post, Wp_2, b2, Y3_t, EOUT);
    stats_kernel<<<dim3(141, NB), 256, 0, stream>>>(Y3_t, stats2, EOUT);
    final_kernel<<<dim3(282, NB), 256, 0, stream>>>(Y3_t, X1_t, stats2, out, EOUT);
}

// Round 4
// 291.697 us; speedup vs baseline: 6.9004x; 1.0371x over previous
//
#include <hip/hip_runtime.h>
#include <math.h>

#define NB 2
#define COUT 128
#define EIN 4500
#define EOUT 9000
#define EPS 1e-5f

typedef __attribute__((ext_vector_type(8))) short bf16x8;
typedef __attribute__((ext_vector_type(4))) float f32x4;

__device__ inline uint32_t bfr(float x) {
    uint32_t u = __float_as_uint(x);
    return (u + 0x7fffu + ((u >> 16) & 1u)) >> 16;
}
__device__ inline uint32_t pk2(float a, float b) { return bfr(a) | (bfr(b) << 16); }
__device__ inline float bf2f(ushort u) { return __uint_as_float((uint32_t)u << 16); }

// ---------- zero stats/parent/pval
__global__ void init_kernel(float* __restrict__ stats, int* __restrict__ parent,
                            float* __restrict__ pval) {
    int i = blockIdx.x * 256 + threadIdx.x;
    if (i < 1024) stats[i] = 0.f;
    if (i < NB * EOUT) { parent[i] = 0; pval[i] = 0.f; }
}

// ---------- tiled transpose f32 [R][C] -> bf16 [C][R], per batch
__global__ void transpose_bf_kernel(const float* __restrict__ in, ushort* __restrict__ out,
                                    int R, int C) {
    __shared__ float tile[32][33];
    int b = blockIdx.z;
    int c0 = blockIdx.x * 32;
    int r0 = blockIdx.y * 32;
    const float* inb = in + (size_t)b * R * C;
    ushort* outb = out + (size_t)b * C * R;
    int tx = threadIdx.x, ty = threadIdx.y;   // 32 x 8
    for (int i = 0; i < 32; i += 8) {
        int r = r0 + ty + i, c = c0 + tx;
        if (r < R && c < C) tile[ty + i][tx] = inb[(size_t)r * C + c];
    }
    __syncthreads();
    for (int i = 0; i < 32; i += 8) {
        int c = c0 + ty + i, r = r0 + tx;
        if (r < R && c < C) outb[(size_t)c * R + r] = (ushort)bfr(tile[tx][ty + i]);
    }
}

// ---------- W [128][CIN][5] f32 -> Wp [128][CIN*8] bf16 (k' = c*8+f, 3 zero pads)
__global__ void wpack_kernel(const float* __restrict__ W, ushort* __restrict__ Wp, int n) {
    int i = blockIdx.x * 256 + threadIdx.x;
    if (i >= n) return;
    const float* src = W + (size_t)i * 5;
    uint4 v;
    v.x = pk2(src[0], src[1]);
    v.y = pk2(src[2], src[3]);
    v.z = pk2(src[4], 0.f);
    v.w = 0u;
    *reinterpret_cast<uint4*>(Wp + (size_t)i * 8) = v;
}

// ---------- coalesced 1-sparse column extraction of unroll_mat
__global__ void parent_scan_kernel(const float* __restrict__ mat, int* __restrict__ parent,
                                   float* __restrict__ pval) {
    const size_t total4 = (size_t)NB * EIN * EOUT / 4;
    size_t stride = (size_t)gridDim.x * blockDim.x;
    for (size_t i = (size_t)blockIdx.x * blockDim.x + threadIdx.x; i < total4; i += stride) {
        float4 v = reinterpret_cast<const float4*>(mat)[i];
        if (v.x != 0.f || v.y != 0.f || v.z != 0.f || v.w != 0.f) {
            float a[4] = {v.x, v.y, v.z, v.w};
#pragma unroll
            for (int j = 0; j < 4; ++j) {
                if (a[j] != 0.f) {
                    size_t idx = i * 4 + j;
                    int eo = (int)(idx % EOUT);
                    size_t t = idx / EOUT;
                    int ei = (int)(t % EIN);
                    int b = (int)(t / EIN);
                    parent[b * EOUT + eo] = ei;
                    pval[b * EOUT + eo] = a[j];
                }
            }
        }
    }
}

// ---------- fused MFMA mesh conv.
// MODE 0 (up):      gather bf16 X[id][c] from Xs (row len CIN)
// MODE 1 (concat):  c<128: Y1[parent[id]][c]*pval[id]; c>=128: FD[id][c-128]
// MODE 2 (normed):  relu((Y2[id][c]-mu1)*rinv1) from raw stats_in
// Output: bf16 [B][E][128]; optional per-(b,c) sum/sumsq atomics into stats_out.
template <int CIN, int MODE, bool STATS>
__global__ __launch_bounds__(256) void conv_mfma(
    const ushort* __restrict__ Xs, const ushort* __restrict__ Aux,
    const int* __restrict__ gm, const int* __restrict__ parent,
    const float* __restrict__ pval, const float* __restrict__ stats_in,
    const ushort* __restrict__ Wp, const float* __restrict__ bias,
    ushort* __restrict__ Out, float* __restrict__ stats_out, int E) {
    constexpr int NCH = CIN / 16;
    constexpr int KP = CIN * 8;
    constexpr int LDW = 136;
    __shared__ __align__(16) ushort Gs[64 * LDW];
    __shared__ __align__(16) ushort Ws[128 * LDW];
    __shared__ int idx[320];
    __shared__ int par[320];
    __shared__ float pv[320];

    int tid = threadIdx.x;
    int b = blockIdx.y, e0 = blockIdx.x * 64;

    for (int i = tid; i < 320; i += 256) {
        int e = i / 5, k = i % 5;
        int eg = e0 + e;
        int id = (eg < E) ? gm[((size_t)b * E + eg) * 5 + k] : 0;
        idx[i] = id;
        if (MODE == 1) {
            par[i] = parent[b * EOUT + id];
            pv[i] = pval[b * EOUT + id];
        }
    }

    int l = tid & 63, w = tid >> 6;
    int lr = l & 15, lg = l >> 4;

    f32x4 acc[4][2];
#pragma unroll
    for (int et = 0; et < 4; ++et)
#pragma unroll
        for (int ot = 0; ot < 2; ++ot) acc[et][ot] = (f32x4)0.f;

    int clc = tid & 15;
    int ebs = tid >> 4;

    for (int ch = 0; ch < NCH; ++ch) {
        __syncthreads();
        // stage W chunk [128 o][128 k']
        {
            int o = tid >> 1, h = tid & 1;
            const ushort* src = Wp + (size_t)o * KP + ch * 128 + h * 64;
            ushort* dst = Ws + o * LDW + h * 64;
#pragma unroll
            for (int i = 0; i < 8; ++i)
                *reinterpret_cast<uint4*>(dst + i * 8) =
                    *reinterpret_cast<const uint4*>(src + i * 8);
        }
        // stage symmetric features: 16 channels x 64 edges
        {
            int c = ch * 16 + clc;
            float mu = 0.f, rinv = 1.f;
            if (MODE == 2) {
                float s = stats_in[(b * 128 + c) * 2 + 0];
                float q = stats_in[(b * 128 + c) * 2 + 1];
                float invE = 1.0f / (float)EOUT;
                mu = s * invE;
                float var = q * invE - mu * mu;
                rinv = rsqrtf(var + EPS);
            }
#pragma unroll
            for (int i = 0; i < 4; ++i) {
                int e = i * 16 + ebs;
                float f[5];
#pragma unroll
                for (int k = 0; k < 5; ++k) {
                    int s5 = e * 5 + k;
                    float val;
                    if (MODE == 0) {
                        val = bf2f(Xs[((size_t)b * E + idx[s5]) * CIN + c]);
                    } else if (MODE == 1) {
                        if (ch < NCH / 2)
                            val = bf2f(Xs[((size_t)b * EIN + par[s5]) * 128 + c]) * pv[s5];
                        else
                            val = bf2f(Aux[((size_t)b * EOUT + idx[s5]) * 128 + (c - 128)]);
                    } else {
                        float y = bf2f(Xs[((size_t)b * E + idx[s5]) * 128 + c]);
                        float z = (y - mu) * rinv;
                        val = z > 0.f ? z : 0.f;
                    }
                    f[k] = val;
                }
                uint4 v;
                v.x = pk2(f[0], f[1] + f[3]);
                v.y = pk2(f[2] + f[4], fabsf(f[1] - f[3]));
                v.z = pk2(fabsf(f[2] - f[4]), 0.f);
                v.w = 0u;
                *reinterpret_cast<uint4*>(Gs + e * LDW + clc * 8) = v;
            }
        }
        __syncthreads();
#pragma unroll
        for (int ks = 0; ks < 4; ++ks) {
            bf16x8 a[4], bb[2];
#pragma unroll
            for (int et = 0; et < 4; ++et)
                a[et] = *reinterpret_cast<const bf16x8*>(Gs + (et * 16 + lr) * LDW + ks * 32 + lg * 8);
#pragma unroll
            for (int ot = 0; ot < 2; ++ot)
                bb[ot] = *reinterpret_cast<const bf16x8*>(Ws + (w * 32 + ot * 16 + lr) * LDW + ks * 32 + lg * 8);
#pragma unroll
            for (int et = 0; et < 4; ++et)
#pragma unroll
                for (int ot = 0; ot < 2; ++ot)
                    acc[et][ot] = __builtin_amdgcn_mfma_f32_16x16x32_bf16(a[et], bb[ot], acc[et][ot], 0, 0, 0);
        }
    }

    // epilogue: D frag: col = lane&15 (=o), row = (lane>>4)*4 + r (=edge)
#pragma unroll
    for (int ot = 0; ot < 2; ++ot) {
        int o = w * 32 + ot * 16 + lr;
        float bv = bias[o];
        float s = 0.f, q = 0.f;
#pragma unroll
        for (int et = 0; et < 4; ++et) {
#pragma unroll
            for (int r = 0; r < 4; ++r) {
                int e = e0 + et * 16 + lg * 4 + r;
                if (e < E) {
                    float y = acc[et][ot][r] + bv;
                    Out[((size_t)b * E + e) * 128 + o] = (ushort)bfr(y);
                    if (STATS) { s += y; q += y * y; }
                }
            }
        }
        if (STATS) {
            s += __shfl_xor(s, 16, 64); s += __shfl_xor(s, 32, 64);
            q += __shfl_xor(q, 16, 64); q += __shfl_xor(q, 32, 64);
            if (lg == 0) {
                atomicAdd(&stats_out[(b * 128 + o) * 2 + 0], s);
                atomicAdd(&stats_out[(b * 128 + o) * 2 + 1], q);
            }
        }
    }
}

// ---------- out[b][c][e] = relu( norm2(Y3) + relu(norm1(Y2)) ), bf16 -> f32 ch-major
__global__ void final_kernel(const ushort* __restrict__ Y3, const ushort* __restrict__ Y2,
                             const float* __restrict__ stats1, const float* __restrict__ stats2,
                             float* __restrict__ out, int E) {
    __shared__ float tile[32 * 129];
    int b = blockIdx.y;
    int e0 = blockIdx.x * 32;
    int tid = threadIdx.x;
    float invE = 1.0f / (float)E;
#pragma unroll
    for (int i = 0; i < 16; ++i) {
        int idx = i * 256 + tid;
        int c = idx & 127, el = idx >> 7;
        int e = e0 + el;
        float v = 0.f;
        if (e < E) {
            float s1 = stats1[(b * 128 + c) * 2 + 0], q1 = stats1[(b * 128 + c) * 2 + 1];
            float mu1 = s1 * invE, var1 = q1 * invE - mu1 * mu1;
            float s2 = stats2[(b * 128 + c) * 2 + 0], q2 = stats2[(b * 128 + c) * 2 + 1];
            float mu2 = s2 * invE, var2 = q2 * invE - mu2 * mu2;
            float x1 = (bf2f(Y2[((size_t)b * E + e) * 128 + c]) - mu1) * rsqrtf(var1 + EPS);
            x1 = x1 > 0.f ? x1 : 0.f;
            float z = (bf2f(Y3[((size_t)b * E + e) * 128 + c]) - mu2) * rsqrtf(var2 + EPS);
            v = z + x1;
            v = v > 0.f ? v : 0.f;
        }
        tile[el * 129 + c] = v;
    }
    __syncthreads();
#pragma unroll
    for (int i = 0; i < 16; ++i) {
        int idx = i * 256 + tid;
        int el = idx & 31, c = idx >> 5;
        int e = e0 + el;
        if (e < E) out[((size_t)b * 128 + c) * E + e] = tile[el * 129 + c];
    }
}

extern "C" void kernel_launch(void* const* d_in, const int* in_sizes, int n_in,
                              void* d_out, int out_size, void* d_ws, size_t ws_size,
                              hipStream_t stream) {
    const float* from_up   = (const float*)d_in[0];
    const float* from_down = (const float*)d_in[1];
    const float* unroll    = (const float*)d_in[2];
    const float* W_up      = (const float*)d_in[3];
    const float* b_up      = (const float*)d_in[4];
    const float* W1        = (const float*)d_in[5];
    const float* b1        = (const float*)d_in[6];
    const float* W2        = (const float*)d_in[7];
    const float* b2        = (const float*)d_in[8];
    const int* gemm_up     = (const int*)d_in[9];
    const int* gemm_post   = (const int*)d_in[10];
    float* out = (float*)d_out;

    float* ws = (float*)d_ws;
    size_t off = 0;
    auto alloc = [&](size_t n) { float* p = ws + off; off += n; return p; };
    ushort* FU_bf = (ushort*)alloc((size_t)NB * EIN * 256 / 2);   // [B][EIN][256] bf16
    ushort* FD_bf = (ushort*)alloc((size_t)NB * EOUT * 128 / 2);  // [B][EOUT][128] bf16
    ushort* Wp_up = (ushort*)alloc(131072);                       // [128][2048]
    ushort* Wp_1  = (ushort*)alloc(131072);
    ushort* Wp_2  = (ushort*)alloc(65536);                        // [128][1024]
    ushort* Y1_bf = (ushort*)alloc((size_t)NB * EIN * 128 / 2);
    ushort* Y2_bf = (ushort*)alloc((size_t)NB * EOUT * 128 / 2);
    ushort* Y3_bf = (ushort*)alloc((size_t)NB * EOUT * 128 / 2);
    float* stats  = alloc(1024);
    int*   parent = (int*)alloc(NB * EOUT);
    float* pval   = alloc(NB * EOUT);
    float* stats1 = stats, *stats2 = stats + 512;

    init_kernel<<<71, 256, 0, stream>>>(stats, parent, pval);

    dim3 tb(32, 8);
    transpose_bf_kernel<<<dim3(141, 8, NB), tb, 0, stream>>>(from_up, FU_bf, 256, EIN);
    transpose_bf_kernel<<<dim3(282, 4, NB), tb, 0, stream>>>(from_down, FD_bf, 128, EOUT);
    wpack_kernel<<<128, 256, 0, stream>>>(W_up, Wp_up, 128 * 256);
    wpack_kernel<<<128, 256, 0, stream>>>(W1, Wp_1, 128 * 256);
    wpack_kernel<<<64, 256, 0, stream>>>(W2, Wp_2, 128 * 128);
    parent_scan_kernel<<<2048, 256, 0, stream>>>(unroll, parent, pval);

    // up conv: FU_bf -> Y1_bf
    conv_mfma<256, 0, false><<<dim3(71, NB), 256, 0, stream>>>(
        FU_bf, nullptr, gemm_up, nullptr, nullptr, nullptr, Wp_up, b_up, Y1_bf, nullptr, EIN);
    // conv1 (fused unpool+concat gather, fused stats1): -> Y2_bf
    conv_mfma<256, 1, true><<<dim3(141, NB), 256, 0, stream>>>(
        Y1_bf, FD_bf, gemm_post, parent, pval, nullptr, Wp_1, b1, Y2_bf, stats1, EOUT);
    // conv2 (fused norm+relu gather, fused stats2): -> Y3_bf
    conv_mfma<128, 2, true><<<dim3(141, NB), 256, 0, stream>>>(
        Y2_bf, nullptr, gemm_post, nullptr, nullptr, stats1, Wp_2, b2, Y3_bf, stats2, EOUT);
    // final: norm2 + residual + relu + transpose to [B][C][E] f32
    final_kernel<<<dim3(282, NB), 256, 0, stream>>>(Y3_bf, Y2_bf, stats1, stats2, out, EOUT);
}

// Round 5
// 232.686 us; speedup vs baseline: 8.6504x; 1.2536x over previous
//
#include <hip/hip_runtime.h>
#include <math.h>

#define NB 2
#define COUT 128
#define EIN 4500
#define EOUT 9000
#define EPS 1e-5f

typedef __attribute__((ext_vector_type(8))) short bf16x8;
typedef __attribute__((ext_vector_type(4))) float f32x4;

__device__ inline uint32_t bfr(float x) {
    uint32_t u = __float_as_uint(x);
    return (u + 0x7fffu + ((u >> 16) & 1u)) >> 16;
}
__device__ inline uint32_t pk2(float a, float b) { return bfr(a) | (bfr(b) << 16); }
__device__ inline float bf2f(ushort u) { return __uint_as_float((uint32_t)u << 16); }

// ---------- merged prep: zero stats/parent/pval + pack all three W into
// per-wave fragment order: Wq[((((w*NCH+ch)*4+ks)*2+ot)*64+lane)*8 + f]
//   o = w*32+ot*16+(lane&15), c = ch*16+ks*4+(lane>>4), f = 0..4 (5..7 zero)
__device__ inline void wpack_frag(const float* __restrict__ W, ushort* __restrict__ Wq,
                                  int i, int CIN) {
    int lane = i & 63; int t = i >> 6;
    int ot = t & 1; t >>= 1;
    int ks = t & 3; t >>= 2;
    int NCH = CIN / 16;
    int ch = t % NCH, w = t / NCH;
    int o = w * 32 + ot * 16 + (lane & 15);
    int c = ch * 16 + ks * 4 + (lane >> 4);
    const float* src = W + ((size_t)o * CIN + c) * 5;
    uint4 v;
    v.x = pk2(src[0], src[1]);
    v.y = pk2(src[2], src[3]);
    v.z = pk2(src[4], 0.f);
    v.w = 0u;
    *reinterpret_cast<uint4*>(Wq + (size_t)i * 8) = v;
}

__global__ void prep_kernel(float* __restrict__ stats, int* __restrict__ parent,
                            float* __restrict__ pval,
                            const float* __restrict__ W_up, ushort* __restrict__ Wq_up,
                            const float* __restrict__ W1, ushort* __restrict__ Wq_1,
                            const float* __restrict__ W2, ushort* __restrict__ Wq_2) {
    int bx = blockIdx.x, tid = threadIdx.x;
    if (bx < 71) {                      // init region
        int i = bx * 256 + tid;
        if (i < 1024) stats[i] = 0.f;
        if (i < NB * EOUT) { parent[i] = 0; pval[i] = 0.f; }
    } else if (bx < 199) {              // Wq_up: 128*256 frag-groups
        wpack_frag(W_up, Wq_up, (bx - 71) * 256 + tid, 256);
    } else if (bx < 327) {              // Wq_1
        wpack_frag(W1, Wq_1, (bx - 199) * 256 + tid, 256);
    } else {                            // Wq_2: 128*128
        wpack_frag(W2, Wq_2, (bx - 327) * 256 + tid, 128);
    }
}

// ---------- tiled transpose f32 [R][C] -> bf16 [C][R], per batch
__global__ void transpose_bf_kernel(const float* __restrict__ in, ushort* __restrict__ out,
                                    int R, int C) {
    __shared__ float tile[32][33];
    int b = blockIdx.z;
    int c0 = blockIdx.x * 32;
    int r0 = blockIdx.y * 32;
    const float* inb = in + (size_t)b * R * C;
    ushort* outb = out + (size_t)b * C * R;
    int tx = threadIdx.x, ty = threadIdx.y;   // 32 x 8
    for (int i = 0; i < 32; i += 8) {
        int r = r0 + ty + i, c = c0 + tx;
        if (r < R && c < C) tile[ty + i][tx] = inb[(size_t)r * C + c];
    }
    __syncthreads();
    for (int i = 0; i < 32; i += 8) {
        int c = c0 + ty + i, r = r0 + tx;
        if (r < R && c < C) outb[(size_t)c * R + r] = (ushort)bfr(tile[tx][ty + i]);
    }
}

// ---------- coalesced 1-sparse column extraction of unroll_mat
__global__ void parent_scan_kernel(const float* __restrict__ mat, int* __restrict__ parent,
                                   float* __restrict__ pval) {
    const size_t total4 = (size_t)NB * EIN * EOUT / 4;
    size_t stride = (size_t)gridDim.x * blockDim.x;
    for (size_t i = (size_t)blockIdx.x * blockDim.x + threadIdx.x; i < total4; i += stride) {
        float4 v = reinterpret_cast<const float4*>(mat)[i];
        if (v.x != 0.f || v.y != 0.f || v.z != 0.f || v.w != 0.f) {
            float a[4] = {v.x, v.y, v.z, v.w};
#pragma unroll
            for (int j = 0; j < 4; ++j) {
                if (a[j] != 0.f) {
                    size_t idx = i * 4 + j;
                    int eo = (int)(idx % EOUT);
                    size_t t = idx / EOUT;
                    int ei = (int)(t % EIN);
                    int b = (int)(t / EIN);
                    parent[b * EOUT + eo] = ei;
                    pval[b * EOUT + eo] = a[j];
                }
            }
        }
    }
}

// ---------- fused MFMA mesh conv (W fragments direct from global).
// MODE 0: gather bf16 Xs[id][c]   MODE 1: unpool(Y1)+concat(FD)   MODE 2: relu(norm(Y2))
template <int CIN, int MODE, bool STATS>
__global__ __launch_bounds__(256) void conv_mfma(
    const ushort* __restrict__ Xs, const ushort* __restrict__ Aux,
    const int* __restrict__ gm, const int* __restrict__ parent,
    const float* __restrict__ pval, const float* __restrict__ stats_in,
    const ushort* __restrict__ Wq, const float* __restrict__ bias,
    ushort* __restrict__ Out, float* __restrict__ stats_out, int E) {
    constexpr int NCH = CIN / 16;
    constexpr int LDW = 136;
    __shared__ __align__(16) ushort Gs[64 * LDW];
    __shared__ int idx[320];
    __shared__ int par[MODE == 1 ? 320 : 1];
    __shared__ float pv[MODE == 1 ? 320 : 1];

    int tid = threadIdx.x;
    int b = blockIdx.y, e0 = blockIdx.x * 64;

    for (int i = tid; i < 320; i += 256) {
        int e = i / 5, k = i % 5;
        int eg = e0 + e;
        int id = (eg < E) ? gm[((size_t)b * E + eg) * 5 + k] : 0;
        idx[i] = id;
        if (MODE == 1) {
            par[i] = parent[b * EOUT + id];
            pv[i] = pval[b * EOUT + id];
        }
    }

    int l = tid & 63, w = tid >> 6;
    int lr = l & 15, lg = l >> 4;

    f32x4 acc[4][2];
#pragma unroll
    for (int et = 0; et < 4; ++et)
#pragma unroll
        for (int ot = 0; ot < 2; ++ot) acc[et][ot] = (f32x4)0.f;

    int cg = tid & 3;        // channel group (4 ch) within 16
    int eb = tid >> 2;       // edge 0..63
    bool evalid = (e0 + eb) < E;
    constexpr int XROW = (MODE == 0) ? CIN : 128;

    for (int ch = 0; ch < NCH; ++ch) {
        __syncthreads();
        // ---- stage symmetric features: 16 channels x 64 edges, 4 ch/thread
        {
            int c0 = ch * 16 + cg * 4;
            uint2 g[5];
#pragma unroll
            for (int k = 0; k < 5; ++k) {
                g[k] = make_uint2(0u, 0u);
                if (evalid) {
                    int s5 = eb * 5 + k;
                    const ushort* src;
                    if (MODE == 1 && ch < NCH / 2)
                        src = Xs + ((size_t)b * EIN + par[s5]) * 128 + c0;
                    else if (MODE == 1)
                        src = Aux + ((size_t)b * EOUT + idx[s5]) * 128 + (c0 - 128);
                    else
                        src = Xs + ((size_t)b * E + idx[s5]) * XROW + c0;
                    g[k] = *reinterpret_cast<const uint2*>(src);
                }
            }
#pragma unroll
            for (int j = 0; j < 4; ++j) {
                float f[5];
#pragma unroll
                for (int k = 0; k < 5; ++k) {
                    uint32_t word = (j < 2) ? g[k].x : g[k].y;
                    ushort h = (j & 1) ? (ushort)(word >> 16) : (ushort)(word & 0xffff);
                    f[k] = bf2f(h);
                }
                if (MODE == 1 && ch < NCH / 2) {
#pragma unroll
                    for (int k = 0; k < 5; ++k) f[k] *= pv[eb * 5 + k];
                } else if (MODE == 2) {
                    int c = ch * 16 + cg * 4 + j;
                    float s = stats_in[(b * 128 + c) * 2 + 0];
                    float q = stats_in[(b * 128 + c) * 2 + 1];
                    float invE = 1.0f / (float)EOUT;
                    float mu = s * invE;
                    float rinv = rsqrtf(q * invE - mu * mu + EPS);
#pragma unroll
                    for (int k = 0; k < 5; ++k) {
                        float z = (f[k] - mu) * rinv;
                        f[k] = z > 0.f ? z : 0.f;
                    }
                }
                uint4 v;
                v.x = pk2(f[0], f[1] + f[3]);
                v.y = pk2(f[2] + f[4], fabsf(f[1] - f[3]));
                v.z = pk2(fabsf(f[2] - f[4]), 0.f);
                v.w = 0u;
                *reinterpret_cast<uint4*>(Gs + eb * LDW + (cg * 4 + j) * 8) = v;
            }
        }
        __syncthreads();
        // ---- MFMA: A from LDS, B fragments straight from global (L2-resident)
        const ushort* wbase = Wq + ((size_t)(w * NCH + ch) * 8 * 64 + l) * 8;
#pragma unroll
        for (int ks = 0; ks < 4; ++ks) {
            bf16x8 a[4], bb[2];
#pragma unroll
            for (int et = 0; et < 4; ++et)
                a[et] = *reinterpret_cast<const bf16x8*>(Gs + (et * 16 + lr) * LDW + ks * 32 + lg * 8);
#pragma unroll
            for (int ot = 0; ot < 2; ++ot)
                bb[ot] = *reinterpret_cast<const bf16x8*>(wbase + ((size_t)(ks * 2 + ot) * 64) * 8);
#pragma unroll
            for (int et = 0; et < 4; ++et)
#pragma unroll
                for (int ot = 0; ot < 2; ++ot)
                    acc[et][ot] = __builtin_amdgcn_mfma_f32_16x16x32_bf16(a[et], bb[ot], acc[et][ot], 0, 0, 0);
        }
    }

    // epilogue: D frag: col = lane&15 (=o), row = (lane>>4)*4 + r (=edge)
#pragma unroll
    for (int ot = 0; ot < 2; ++ot) {
        int o = w * 32 + ot * 16 + lr;
        float bv = bias[o];
        float s = 0.f, q = 0.f;
#pragma unroll
        for (int et = 0; et < 4; ++et) {
#pragma unroll
            for (int r = 0; r < 4; ++r) {
                int e = e0 + et * 16 + lg * 4 + r;
                if (e < E) {
                    float y = acc[et][ot][r] + bv;
                    Out[((size_t)b * E + e) * 128 + o] = (ushort)bfr(y);
                    if (STATS) { s += y; q += y * y; }
                }
            }
        }
        if (STATS) {
            s += __shfl_xor(s, 16, 64); s += __shfl_xor(s, 32, 64);
            q += __shfl_xor(q, 16, 64); q += __shfl_xor(q, 32, 64);
            if (lg == 0) {
                atomicAdd(&stats_out[(b * 128 + o) * 2 + 0], s);
                atomicAdd(&stats_out[(b * 128 + o) * 2 + 1], q);
            }
        }
    }
}

// ---------- out[b][c][e] = relu( norm2(Y3) + relu(norm1(Y2)) ), bf16 -> f32 ch-major
__global__ void final_kernel(const ushort* __restrict__ Y3, const ushort* __restrict__ Y2,
                             const float* __restrict__ stats1, const float* __restrict__ stats2,
                             float* __restrict__ out, int E) {
    __shared__ float tile[32 * 129];
    int b = blockIdx.y;
    int e0 = blockIdx.x * 32;
    int tid = threadIdx.x;
    float invE = 1.0f / (float)E;
#pragma unroll
    for (int i = 0; i < 16; ++i) {
        int idx = i * 256 + tid;
        int c = idx & 127, el = idx >> 7;
        int e = e0 + el;
        float v = 0.f;
        if (e < E) {
            float s1 = stats1[(b * 128 + c) * 2 + 0], q1 = stats1[(b * 128 + c) * 2 + 1];
            float mu1 = s1 * invE, var1 = q1 * invE - mu1 * mu1;
            float s2 = stats2[(b * 128 + c) * 2 + 0], q2 = stats2[(b * 128 + c) * 2 + 1];
            float mu2 = s2 * invE, var2 = q2 * invE - mu2 * mu2;
            float x1 = (bf2f(Y2[((size_t)b * E + e) * 128 + c]) - mu1) * rsqrtf(var1 + EPS);
            x1 = x1 > 0.f ? x1 : 0.f;
            float z = (bf2f(Y3[((size_t)b * E + e) * 128 + c]) - mu2) * rsqrtf(var2 + EPS);
            v = z + x1;
            v = v > 0.f ? v : 0.f;
        }
        tile[el * 129 + c] = v;
    }
    __syncthreads();
#pragma unroll
    for (int i = 0; i < 16; ++i) {
        int idx = i * 256 + tid;
        int el = idx & 31, c = idx >> 5;
        int e = e0 + el;
        if (e < E) out[((size_t)b * 128 + c) * E + e] = tile[el * 129 + c];
    }
}

extern "C" void kernel_launch(void* const* d_in, const int* in_sizes, int n_in,
                              void* d_out, int out_size, void* d_ws, size_t ws_size,
                              hipStream_t stream) {
    const float* from_up   = (const float*)d_in[0];
    const float* from_down = (const float*)d_in[1];
    const float* unroll    = (const float*)d_in[2];
    const float* W_up      = (const float*)d_in[3];
    const float* b_up      = (const float*)d_in[4];
    const float* W1        = (const float*)d_in[5];
    const float* b1        = (const float*)d_in[6];
    const float* W2        = (const float*)d_in[7];
    const float* b2        = (const float*)d_in[8];
    const int* gemm_up     = (const int*)d_in[9];
    const int* gemm_post   = (const int*)d_in[10];
    float* out = (float*)d_out;

    float* ws = (float*)d_ws;
    size_t off = 0;
    auto alloc = [&](size_t n) { float* p = ws + off; off += n; return p; };
    ushort* FU_bf = (ushort*)alloc((size_t)NB * EIN * 256 / 2);   // [B][EIN][256] bf16
    ushort* FD_bf = (ushort*)alloc((size_t)NB * EOUT * 128 / 2);  // [B][EOUT][128] bf16
    ushort* Wq_up = (ushort*)alloc(131072);                       // 128*2048 bf16 frag order
    ushort* Wq_1  = (ushort*)alloc(131072);
    ushort* Wq_2  = (ushort*)alloc(65536);                        // 128*1024
    ushort* Y1_bf = (ushort*)alloc((size_t)NB * EIN * 128 / 2);
    ushort* Y2_bf = (ushort*)alloc((size_t)NB * EOUT * 128 / 2);
    ushort* Y3_bf = (ushort*)alloc((size_t)NB * EOUT * 128 / 2);
    float* stats  = alloc(1024);
    int*   parent = (int*)alloc(NB * EOUT);
    float* pval   = alloc(NB * EOUT);
    float* stats1 = stats, *stats2 = stats + 512;

    prep_kernel<<<391, 256, 0, stream>>>(stats, parent, pval,
                                         W_up, Wq_up, W1, Wq_1, W2, Wq_2);

    dim3 tb(32, 8);
    transpose_bf_kernel<<<dim3(141, 8, NB), tb, 0, stream>>>(from_up, FU_bf, 256, EIN);
    transpose_bf_kernel<<<dim3(282, 4, NB), tb, 0, stream>>>(from_down, FD_bf, 128, EOUT);
    parent_scan_kernel<<<2048, 256, 0, stream>>>(unroll, parent, pval);

    // up conv: FU_bf -> Y1_bf
    conv_mfma<256, 0, false><<<dim3(71, NB), 256, 0, stream>>>(
        FU_bf, nullptr, gemm_up, nullptr, nullptr, nullptr, Wq_up, b_up, Y1_bf, nullptr, EIN);
    // conv1 (fused unpool+concat gather, fused stats1): -> Y2_bf
    conv_mfma<256, 1, true><<<dim3(141, NB), 256, 0, stream>>>(
        Y1_bf, FD_bf, gemm_post, parent, pval, nullptr, Wq_1, b1, Y2_bf, stats1, EOUT);
    // conv2 (fused norm+relu gather, fused stats2): -> Y3_bf
    conv_mfma<128, 2, true><<<dim3(141, NB), 256, 0, stream>>>(
        Y2_bf, nullptr, gemm_post, nullptr, nullptr, stats1, Wq_2, b2, Y3_bf, stats2, EOUT);
    // final: norm2 + residual + relu + transpose to [B][C][E] f32
    final_kernel<<<dim3(282, NB), 256, 0, stream>>>(Y3_bf, Y2_bf, stats1, stats2, out, EOUT);
}

// Round 7
// 183.355 us; speedup vs baseline: 10.9777x; 1.2690x over previous
//
#include <hip/hip_runtime.h>
#include <hip/hip_bf16.h>
#include <math.h>

#define NB 2
#define EIN 4500
#define EOUT 9000
#define EPS 1e-5f

typedef __attribute__((ext_vector_type(8))) short bf16x8;
typedef __attribute__((ext_vector_type(4))) float f32x4;

__device__ inline uint32_t bfr(float x) {
    uint32_t u = __float_as_uint(x);
    return (u + 0x7fffu + ((u >> 16) & 1u)) >> 16;
}
__device__ inline uint32_t pk2(float a, float b) {
    __hip_bfloat162 h = __float22bfloat162_rn(make_float2(a, b));   // v_cvt_pk_bf16_f32
    uint32_t u;
    __builtin_memcpy(&u, &h, 4);
    return u;
}
__device__ inline float bf2f(ushort u) { return __uint_as_float((uint32_t)u << 16); }

// ---------- W pack into per-wave fragment order:
// Wq[((((w*NCH+ch)*4+ks)*2+ot)*64+lane)*8 + f], o=w*32+ot*16+(lane&15), c=ch*16+ks*4+(lane>>4)
__device__ inline void wpack_frag(const float* __restrict__ W, ushort* __restrict__ Wq,
                                  int i, int CIN) {
    int lane = i & 63; int t = i >> 6;
    int ot = t & 1; t >>= 1;
    int ks = t & 3; t >>= 2;
    int NCH = CIN / 16;
    int ch = t % NCH, w = t / NCH;
    int o = w * 32 + ot * 16 + (lane & 15);
    int c = ch * 16 + ks * 4 + (lane >> 4);
    const float* src = W + ((size_t)o * CIN + c) * 5;
    uint4 v;
    v.x = pk2(src[0], src[1]);
    v.y = pk2(src[2], src[3]);
    v.z = pk2(src[4], 0.f);
    v.w = 0u;
    *reinterpret_cast<uint4*>(Wq + (size_t)i * 8) = v;
}

// ---------- tiled transpose f32 [R][C] -> bf16 [C][R] (one 32x32 tile per call)
__device__ inline void transpose_bf_body(float (*tile)[33], const float* __restrict__ in,
                                         ushort* __restrict__ out, int R, int C,
                                         int id, int nbx, int nby, int tid) {
    int bxt = id % nbx; int rest = id / nbx;
    int by = rest % nby; int b = rest / nby;
    int c0 = bxt * 32, r0 = by * 32;
    const float* inb = in + (size_t)b * R * C;
    ushort* outb = out + (size_t)b * C * R;
    int tx = tid & 31, ty = tid >> 5;   // 32 x 8
#pragma unroll
    for (int i = 0; i < 4; ++i) {
        int r = r0 + ty + i * 8, c = c0 + tx;
        if (r < R && c < C) tile[ty + i * 8][tx] = inb[(size_t)r * C + c];
    }
    __syncthreads();
#pragma unroll
    for (int i = 0; i < 4; ++i) {
        int c = c0 + ty + i * 8, r = r0 + tx;
        if (r < R && c < C) outb[(size_t)c * R + r] = (ushort)bfr(tile[tx][ty + i * 8]);
    }
}

// ---------- phase0: scan + transposes + wpack + stats-zero fused.
// NOTE: parent/pval are NOT zero-initialized — the unpool matrix has exactly one
// nonzero per column, so the scan overwrites every (b,eo) deterministically.
// (Zeroing them here raced with the scan in R6 — blocks run in undefined order.)
#define SCAN_B 2048
#define FU_B 2256     // 141 x 8 x 2
#define FD_B 2256     // 282 x 4 x 2
#define WP_B 320      // 81920 / 256
#define INIT_B 1      // stats only (1024 floats)
__global__ __launch_bounds__(256) void phase0_kernel(
    const float* __restrict__ unroll, int* __restrict__ parent, float* __restrict__ pval,
    const float* __restrict__ from_up, ushort* __restrict__ FU,
    const float* __restrict__ from_down, ushort* __restrict__ FD,
    const float* __restrict__ W_up, ushort* __restrict__ Wq_up,
    const float* __restrict__ W1, ushort* __restrict__ Wq_1,
    const float* __restrict__ W2, ushort* __restrict__ Wq_2,
    float* __restrict__ stats) {
    __shared__ float tile[32][33];
    int bx = blockIdx.x, tid = threadIdx.x;
    if (bx < SCAN_B) {
        // coalesced 1-sparse column extraction of unroll_mat
        const size_t total4 = (size_t)NB * EIN * EOUT / 4;
        const size_t stride = (size_t)SCAN_B * 256;
        for (size_t i = (size_t)bx * 256 + tid; i < total4; i += stride) {
            float4 v = reinterpret_cast<const float4*>(unroll)[i];
            if (v.x != 0.f || v.y != 0.f || v.z != 0.f || v.w != 0.f) {
                float a[4] = {v.x, v.y, v.z, v.w};
#pragma unroll
                for (int j = 0; j < 4; ++j) {
                    if (a[j] != 0.f) {
                        size_t idx = i * 4 + j;
                        int eo = (int)(idx % EOUT);
                        size_t t = idx / EOUT;
                        int ei = (int)(t % EIN);
                        int b = (int)(t / EIN);
                        parent[b * EOUT + eo] = ei;
                        pval[b * EOUT + eo] = a[j];
                    }
                }
            }
        }
    } else if (bx < SCAN_B + FU_B) {
        transpose_bf_body(tile, from_up, FU, 256, EIN, bx - SCAN_B, 141, 8, tid);
    } else if (bx < SCAN_B + FU_B + FD_B) {
        transpose_bf_body(tile, from_down, FD, 128, EOUT, bx - (SCAN_B + FU_B), 282, 4, tid);
    } else if (bx < SCAN_B + FU_B + FD_B + WP_B) {
        int i = (bx - (SCAN_B + FU_B + FD_B)) * 256 + tid;
        if (i < 32768) wpack_frag(W_up, Wq_up, i, 256);
        else if (i < 65536) wpack_frag(W1, Wq_1, i - 32768, 256);
        else wpack_frag(W2, Wq_2, i - 65536, 128);
    } else {
        // stats zero (required every call: conv epilogues accumulate atomically)
#pragma unroll
        for (int j = 0; j < 4; ++j) stats[j * 256 + tid] = 0.f;
    }
}

// ---------- fused MFMA mesh conv, double-buffered LDS, 1 barrier/chunk.
// MODE 0: gather bf16 Xs[id][c]   MODE 1: unpool(Y1)+concat(FD)   MODE 2: relu(norm(Y2))
template <int CIN, int MODE, bool STATS>
__global__ __launch_bounds__(256) void conv_mfma(
    const ushort* __restrict__ Xs, const ushort* __restrict__ Aux,
    const int* __restrict__ gm, const int* __restrict__ parent,
    const float* __restrict__ pval, const float* __restrict__ stats_in,
    const ushort* __restrict__ Wq, const float* __restrict__ bias,
    ushort* __restrict__ Out, float* __restrict__ stats_out, int E) {
    constexpr int NCH = CIN / 16;
    constexpr int LDW = 136;
    constexpr int GSZ = 64 * LDW;
    __shared__ __align__(16) ushort Gs[2 * GSZ];
    __shared__ int idx[320];
    __shared__ int par[MODE == 1 ? 320 : 1];
    __shared__ float pv[MODE == 1 ? 320 : 1];
    __shared__ float muS[MODE == 2 ? 128 : 1];
    __shared__ float rinvS[MODE == 2 ? 128 : 1];

    int tid = threadIdx.x;
    int b = blockIdx.y, e0 = blockIdx.x * 64;

    for (int i = tid; i < 320; i += 256) {
        int e = i / 5, k = i % 5;
        int eg = e0 + e;
        int id = (eg < E) ? gm[((size_t)b * E + eg) * 5 + k] : 0;
        idx[i] = id;
        if (MODE == 1) {
            par[i] = parent[b * EOUT + id];
            pv[i] = pval[b * EOUT + id];
        }
    }
    if (MODE == 2 && tid < 128) {
        float s = stats_in[(b * 128 + tid) * 2 + 0];
        float q = stats_in[(b * 128 + tid) * 2 + 1];
        float invE = 1.0f / (float)EOUT;
        float mu = s * invE;
        muS[tid] = mu;
        rinvS[tid] = rsqrtf(q * invE - mu * mu + EPS);
    }
    __syncthreads();

    int l = tid & 63, w = tid >> 6;
    int lr = l & 15, lg = l >> 4;
    int cg = tid & 3, eb = tid >> 2;
    bool evalid = (e0 + eb) < E;
    constexpr int XROW = (MODE == 0) ? CIN : 128;

    f32x4 acc[4][2];
#pragma unroll
    for (int et = 0; et < 4; ++et)
#pragma unroll
        for (int ot = 0; ot < 2; ++ot) acc[et][ot] = (f32x4)0.f;

    uint2 g[5];
    auto loadG = [&](int ch) {
        int c0 = ch * 16 + cg * 4;
#pragma unroll
        for (int k = 0; k < 5; ++k) {
            g[k] = make_uint2(0u, 0u);
            if (evalid) {
                int s5 = eb * 5 + k;
                const ushort* src;
                if (MODE == 1) {
                    if (ch < NCH / 2) src = Xs + ((size_t)b * EIN + par[s5]) * 128 + c0;
                    else src = Aux + ((size_t)b * EOUT + idx[s5]) * 128 + (c0 - 128);
                } else {
                    src = Xs + ((size_t)b * E + idx[s5]) * XROW + c0;
                }
                g[k] = *reinterpret_cast<const uint2*>(src);
            }
        }
    };

    auto stageG = [&](int ch, ushort* gbuf) {
        float pvr[5];
        if (MODE == 1 && ch < NCH / 2) {
#pragma unroll
            for (int k = 0; k < 5; ++k) pvr[k] = pv[eb * 5 + k];
        }
#pragma unroll
        for (int j = 0; j < 4; ++j) {
            float f[5];
#pragma unroll
            for (int k = 0; k < 5; ++k) {
                uint32_t word = (j < 2) ? g[k].x : g[k].y;
                ushort h = (j & 1) ? (ushort)(word >> 16) : (ushort)(word & 0xffff);
                f[k] = bf2f(h);
            }
            if (MODE == 1 && ch < NCH / 2) {
#pragma unroll
                for (int k = 0; k < 5; ++k) f[k] *= pvr[k];
            } else if (MODE == 2) {
                int c = ch * 16 + cg * 4 + j;
                float mu = muS[c], rinv = rinvS[c];
#pragma unroll
                for (int k = 0; k < 5; ++k) {
                    float z = (f[k] - mu) * rinv;
                    f[k] = z > 0.f ? z : 0.f;
                }
            }
            uint4 v;
            v.x = pk2(f[0], f[1] + f[3]);
            v.y = pk2(f[2] + f[4], fabsf(f[1] - f[3]));
            v.z = pk2(fabsf(f[2] - f[4]), 0.f);
            v.w = 0u;
            *reinterpret_cast<uint4*>(gbuf + eb * LDW + (cg * 4 + j) * 8) = v;
        }
    };

    loadG(0);
    for (int ch = 0; ch < NCH; ++ch) {
        ushort* gbuf = Gs + (ch & 1) * GSZ;
        stageG(ch, gbuf);             // write buf[ch&1]: prior reader MFMA(ch-2) fenced by bar(ch-1)
        __syncthreads();
        if (ch + 1 < NCH) loadG(ch + 1);   // issue next gathers; latency hides under MFMA
        const ushort* wbase = Wq + ((size_t)(w * NCH + ch) * 8 * 64 + l) * 8;
#pragma unroll
        for (int ks = 0; ks < 4; ++ks) {
            bf16x8 a[4], bb[2];
#pragma unroll
            for (int et = 0; et < 4; ++et)
                a[et] = *reinterpret_cast<const bf16x8*>(gbuf + (et * 16 + lr) * LDW + ks * 32 + lg * 8);
#pragma unroll
            for (int ot = 0; ot < 2; ++ot)
                bb[ot] = *reinterpret_cast<const bf16x8*>(wbase + ((size_t)(ks * 2 + ot) * 64) * 8);
#pragma unroll
            for (int et = 0; et < 4; ++et)
#pragma unroll
                for (int ot = 0; ot < 2; ++ot)
                    acc[et][ot] = __builtin_amdgcn_mfma_f32_16x16x32_bf16(a[et], bb[ot], acc[et][ot], 0, 0, 0);
        }
    }

    // epilogue: D frag: col = lane&15 (=o), row = (lane>>4)*4 + r (=edge)
#pragma unroll
    for (int ot = 0; ot < 2; ++ot) {
        int o = w * 32 + ot * 16 + lr;
        float bv = bias[o];
        float s = 0.f, q = 0.f;
#pragma unroll
        for (int et = 0; et < 4; ++et) {
#pragma unroll
            for (int r = 0; r < 4; ++r) {
                int e = e0 + et * 16 + lg * 4 + r;
                if (e < E) {
                    float y = acc[et][ot][r] + bv;
                    Out[((size_t)b * E + e) * 128 + o] = (ushort)bfr(y);
                    if (STATS) { s += y; q += y * y; }
                }
            }
        }
        if (STATS) {
            s += __shfl_xor(s, 16, 64); s += __shfl_xor(s, 32, 64);
            q += __shfl_xor(q, 16, 64); q += __shfl_xor(q, 32, 64);
            if (lg == 0) {
                atomicAdd(&stats_out[(b * 128 + o) * 2 + 0], s);
                atomicAdd(&stats_out[(b * 128 + o) * 2 + 1], q);
            }
        }
    }
}

// ---------- out[b][c][e] = relu( norm2(Y3) + relu(norm1(Y2)) ), bf16 -> f32 ch-major
__global__ void final_kernel(const ushort* __restrict__ Y3, const ushort* __restrict__ Y2,
                             const float* __restrict__ stats1, const float* __restrict__ stats2,
                             float* __restrict__ out, int E) {
    __shared__ float tile[32 * 129];
    int b = blockIdx.y;
    int e0 = blockIdx.x * 32;
    int tid = threadIdx.x;
    float invE = 1.0f / (float)E;
#pragma unroll
    for (int i = 0; i < 16; ++i) {
        int idx = i * 256 + tid;
        int c = idx & 127, el = idx >> 7;
        int e = e0 + el;
        float v = 0.f;
        if (e < E) {
            float s1 = stats1[(b * 128 + c) * 2 + 0], q1 = stats1[(b * 128 + c) * 2 + 1];
            float mu1 = s1 * invE, var1 = q1 * invE - mu1 * mu1;
            float s2 = stats2[(b * 128 + c) * 2 + 0], q2 = stats2[(b * 128 + c) * 2 + 1];
            float mu2 = s2 * invE, var2 = q2 * invE - mu2 * mu2;
            float x1 = (bf2f(Y2[((size_t)b * E + e) * 128 + c]) - mu1) * rsqrtf(var1 + EPS);
            x1 = x1 > 0.f ? x1 : 0.f;
            float z = (bf2f(Y3[((size_t)b * E + e) * 128 + c]) - mu2) * rsqrtf(var2 + EPS);
            v = z + x1;
            v = v > 0.f ? v : 0.f;
        }
        tile[el * 129 + c] = v;
    }
    __syncthreads();
#pragma unroll
    for (int i = 0; i < 16; ++i) {
        int idx = i * 256 + tid;
        int el = idx & 31, c = idx >> 5;
        int e = e0 + el;
        if (e < E) out[((size_t)b * 128 + c) * E + e] = tile[el * 129 + c];
    }
}

extern "C" void kernel_launch(void* const* d_in, const int* in_sizes, int n_in,
                              void* d_out, int out_size, void* d_ws, size_t ws_size,
                              hipStream_t stream) {
    const float* from_up   = (const float*)d_in[0];
    const float* from_down = (const float*)d_in[1];
    const float* unroll    = (const float*)d_in[2];
    const float* W_up      = (const float*)d_in[3];
    const float* b_up      = (const float*)d_in[4];
    const float* W1        = (const float*)d_in[5];
    const float* b1        = (const float*)d_in[6];
    const float* W2        = (const float*)d_in[7];
    const float* b2        = (const float*)d_in[8];
    const int* gemm_up     = (const int*)d_in[9];
    const int* gemm_post   = (const int*)d_in[10];
    float* out = (float*)d_out;

    float* ws = (float*)d_ws;
    size_t off = 0;
    auto alloc = [&](size_t n) { float* p = ws + off; off += n; return p; };
    ushort* FU_bf = (ushort*)alloc((size_t)NB * EIN * 256 / 2);   // [B][EIN][256] bf16
    ushort* FD_bf = (ushort*)alloc((size_t)NB * EOUT * 128 / 2);  // [B][EOUT][128] bf16
    ushort* Wq_up = (ushort*)alloc(131072);                       // frag order
    ushort* Wq_1  = (ushort*)alloc(131072);
    ushort* Wq_2  = (ushort*)alloc(65536);
    ushort* Y1_bf = (ushort*)alloc((size_t)NB * EIN * 128 / 2);
    ushort* Y2_bf = (ushort*)alloc((size_t)NB * EOUT * 128 / 2);
    ushort* Y3_bf = (ushort*)alloc((size_t)NB * EOUT * 128 / 2);
    float* stats  = alloc(1024);
    int*   parent = (int*)alloc(NB * EOUT);
    float* pval   = alloc(NB * EOUT);
    float* stats1 = stats, *stats2 = stats + 512;

    phase0_kernel<<<SCAN_B + FU_B + FD_B + WP_B + INIT_B, 256, 0, stream>>>(
        unroll, parent, pval, from_up, FU_bf, from_down, FD_bf,
        W_up, Wq_up, W1, Wq_1, W2, Wq_2, stats);

    // up conv: FU_bf -> Y1_bf
    conv_mfma<256, 0, false><<<dim3(71, NB), 256, 0, stream>>>(
        FU_bf, nullptr, gemm_up, nullptr, nullptr, nullptr, Wq_up, b_up, Y1_bf, nullptr, EIN);
    // conv1 (fused unpool+concat gather, fused stats1): -> Y2_bf
    conv_mfma<256, 1, true><<<dim3(141, NB), 256, 0, stream>>>(
        Y1_bf, FD_bf, gemm_post, parent, pval, nullptr, Wq_1, b1, Y2_bf, stats1, EOUT);
    // conv2 (fused norm+relu gather, fused stats2): -> Y3_bf
    conv_mfma<128, 2, true><<<dim3(141, NB), 256, 0, stream>>>(
        Y2_bf, nullptr, gemm_post, nullptr, nullptr, stats1, Wq_2, b2, Y3_bf, stats2, EOUT);
    // final: norm2 + residual + relu + transpose to [B][C][E] f32
    final_kernel<<<dim3(282, NB), 256, 0, stream>>>(Y3_bf, Y2_bf, stats1, stats2, out, EOUT);
}